// Round 15
// baseline (316.951 us; speedup 1.0000x reference)
//
#include <hip/hip_runtime.h>
#include <math.h>

#define NN 50000
#define EE 600000
#define DD 128
#define GG 64
#define NCLS 10
#define PCHUNK 128
#define NTILE (NN / 16)            // 3125 row-tiles, exact
#define NBUK 196                   // buckets of 256 dst nodes (dst>>8)
#define BSTRIDE 4096               // slots per bucket (mean 3072, sigma 55)
#define EPB ((EE + 255) / 256)     // 2344 edges per pass-1 block
#define KVROW 384                  // bytes: 128 fp8 k + 256 bf16 v

typedef __attribute__((ext_vector_type(8))) __bf16 bf16x8;
typedef __attribute__((ext_vector_type(8))) unsigned short u16x8;
typedef __attribute__((ext_vector_type(4))) float f32x4;
typedef __attribute__((ext_vector_type(2))) float f32x2;

__device__ __forceinline__ unsigned short f2bf(float f) {
    unsigned int u = __float_as_uint(f);
    u += 0x7fff + ((u >> 16) & 1);     // round-to-nearest-even
    return (unsigned short)(u >> 16);
}

__device__ __forceinline__ float bf2f(unsigned short h) {
    return __uint_as_float(((unsigned int)h) << 16);
}

__device__ __forceinline__ unsigned char f2fp8(float f) {
    // OCP e4m3fn via HW packed convert (saturating, RNE)
    return (unsigned char)(__builtin_amdgcn_cvt_pk_fp8_f32(f, f, 0, false) & 0xFF);
}

// ---------------- fused prep: zero bucketcnt/gsum + wt convert --------------

__global__ __launch_bounds__(256) void prep_kernel(
    const float* __restrict__ wq, const float* __restrict__ wk,
    const float* __restrict__ wv, const float* __restrict__ ws,
    unsigned short* __restrict__ wt,
    int* __restrict__ bucketcnt, float* __restrict__ gsum) {
    int tid = blockIdx.x * 256 + threadIdx.x;
    int TOT = gridDim.x * 256;
    if (tid < 256) bucketcnt[tid] = 0;
    for (int i = tid; i < GG * DD + GG; i += TOT) gsum[i] = 0.f;
    for (int i = tid; i < 2 * 4 * 16384; i += TOT) {
        int k = i & 127;
        int n = (i >> 7) & 127;
        int lm = i >> 14;
        int l = lm >> 2, m = lm & 3;
        const float* w = (m == 0) ? wq : (m == 1) ? wk : (m == 2) ? wv : ws;
        wt[i] = f2bf(w[l * 16384 + k * 128 + n]);
    }
}

// ---------------- CSR pass 1: bucket by dst>>8 ------------------------------

__global__ __launch_bounds__(1024) void bucket_kernel(
    const int* __restrict__ src, const int* __restrict__ dst,
    int* __restrict__ bucketcnt, int2* __restrict__ bedge) {
    __shared__ int hist[256];
    __shared__ int base[256];
    int t = threadIdx.x;
    if (t < 256) hist[t] = 0;
    __syncthreads();
    int e0 = blockIdx.x * EPB;
    int eend = min(e0 + EPB, EE);

    int b0 = -1, b1 = -1, b2 = -1;
    int sl0 = 0, sl1 = 0, sl2 = 0;
    int s0 = 0, s1 = 0, s2 = 0, d0 = 0, d1 = 0, d2 = 0;
    int i = e0 + t;
    if (i < eend) { d0 = dst[i]; s0 = src[i]; b0 = d0 >> 8; sl0 = atomicAdd(&hist[b0], 1); }
    i += 1024;
    if (i < eend) { d1 = dst[i]; s1 = src[i]; b1 = d1 >> 8; sl1 = atomicAdd(&hist[b1], 1); }
    i += 1024;
    if (i < eend) { d2 = dst[i]; s2 = src[i]; b2 = d2 >> 8; sl2 = atomicAdd(&hist[b2], 1); }
    __syncthreads();

    if (t < 256) {
        int h = hist[t];
        base[t] = h ? atomicAdd(&bucketcnt[t], h) : 0;
    }
    __syncthreads();

    if (b0 >= 0) bedge[b0 * BSTRIDE + base[b0] + sl0] = make_int2(s0, d0);
    if (b1 >= 0) bedge[b1 * BSTRIDE + base[b1] + sl1] = make_int2(s1, d1);
    if (b2 >= 0) bedge[b2 * BSTRIDE + base[b2] + sl2] = make_int2(s2, d2);
}

// ---------------- CSR pass 2: per-bucket node sort -> indptr + esrc ---------

__global__ __launch_bounds__(1024) void bsort_kernel(
    const int* __restrict__ bucketcnt, const int2* __restrict__ bedge,
    int* __restrict__ indptr, int* __restrict__ esrc) {
    __shared__ int buf[256];
    __shared__ int cur[256];
    int b = blockIdx.x;
    int t = threadIdx.x;

    if (t < 256) buf[t] = (t < NBUK) ? bucketcnt[t] : 0;
    __syncthreads();
    if (t < 64) {
        int carry = 0;
        #pragma unroll
        for (int c = 0; c < 4; ++c) {
            int v = buf[c * 64 + t];
            int x = v;
            #pragma unroll
            for (int off = 1; off < 64; off <<= 1) {
                int y = __shfl_up(x, off);
                if (t >= off) x += y;
            }
            cur[c * 64 + t] = carry + x - v;
            carry += __shfl(x, 63);
        }
    }
    __syncthreads();
    int count = buf[b];
    int bstart = cur[b];
    int node0 = b << 8;
    int nn = min(256, NN - node0);
    if (b == 0 && t == 0) indptr[NN] = EE;
    __syncthreads();
    if (t < 256) buf[t] = 0;
    __syncthreads();

    const int2* be = bedge + (size_t)b * BSTRIDE;
    for (int i2 = t; i2 < count; i2 += 1024)
        atomicAdd(&buf[be[i2].y - node0], 1);
    __syncthreads();

    if (t < 64) {
        int carry = 0;
        #pragma unroll
        for (int c = 0; c < 4; ++c) {
            int v = buf[c * 64 + t];
            int x = v;
            #pragma unroll
            for (int off = 1; off < 64; off <<= 1) {
                int y = __shfl_up(x, off);
                if (t >= off) x += y;
            }
            cur[c * 64 + t] = carry + x - v;
            carry += __shfl(x, 63);
        }
    }
    __syncthreads();
    if (t < nn) indptr[node0 + t] = bstart + cur[t];
    __syncthreads();

    for (int i2 = t; i2 < count; i2 += 1024) {
        int2 e = be[i2];
        int slot = atomicAdd(&cur[e.y - node0], 1);
        esrc[bstart + slot] = e.x;
    }
}

// ---------------- persistent-wave LDS-free bf16 MFMA GEMM (R10 winner) -----
// kv row: [128 fp8 k | 128 bf16 v] = 384 B. k stored fp8-e4m3 (score-only
// consumer tolerates ~3% rel err; halves k gather bytes + unpack VALU).

template <bool IN_BF16>
__global__ __launch_bounds__(256, 4) void gemm_mfma(
    const void* __restrict__ xin,
    const unsigned short* __restrict__ wt,      // [4][128][128] bf16, n-major
    const float* __restrict__ bq, const float* __restrict__ bk,
    const float* __restrict__ bv, const float* __restrict__ bs,
    unsigned short* __restrict__ qb, unsigned char* __restrict__ kvb,
    unsigned short* __restrict__ sb) {
    int gw = blockIdx.x * 4 + (threadIdx.x >> 6);   // 0..2047
    int lane = threadIdx.x & 63;
    int mat = (gw >> 1) & 3;
    int ch = gw & 1;
    int wseq = gw >> 3;                              // 0..255
    int lr = lane & 15, quad = lane >> 4;

    const unsigned short* wm_ = wt + mat * 16384;
    const float* bias = (mat == 0) ? bq : (mat == 1) ? bk : (mat == 2) ? bv : bs;

    bf16x8 bfr[4][4];
    #pragma unroll
    for (int ks = 0; ks < 4; ++ks)
        #pragma unroll
        for (int tn = 0; tn < 4; ++tn)
            bfr[ks][tn] = *(const bf16x8*)(wm_ + (ch * 64 + tn * 16 + lr) * 128
                                               + ks * 32 + quad * 8);
    float bcol[4];
    #pragma unroll
    for (int tn = 0; tn < 4; ++tn) bcol[tn] = bias[ch * 64 + tn * 16 + lr];

    for (int tile = wseq; tile < NTILE; tile += 256) {
        int row0 = tile * 16;
        bf16x8 af[4];
        #pragma unroll
        for (int ks = 0; ks < 4; ++ks) {
            if (IN_BF16) {
                af[ks] = *(const bf16x8*)((const unsigned short*)xin
                             + (size_t)(row0 + lr) * DD + ks * 32 + quad * 8);
            } else {
                const float* p = (const float*)xin
                                 + (size_t)(row0 + lr) * DD + ks * 32 + quad * 8;
                float4 f0 = *(const float4*)p;
                float4 f1 = *(const float4*)(p + 4);
                u16x8 a8;
                a8[0] = f2bf(f0.x); a8[1] = f2bf(f0.y); a8[2] = f2bf(f0.z); a8[3] = f2bf(f0.w);
                a8[4] = f2bf(f1.x); a8[5] = f2bf(f1.y); a8[6] = f2bf(f1.z); a8[7] = f2bf(f1.w);
                af[ks] = *(bf16x8*)&a8;
            }
        }

        f32x4 acc[4];
        #pragma unroll
        for (int tn = 0; tn < 4; ++tn) acc[tn] = (f32x4){0.f, 0.f, 0.f, 0.f};
        #pragma unroll
        for (int ks = 0; ks < 4; ++ks)
            #pragma unroll
            for (int tn = 0; tn < 4; ++tn)
                acc[tn] = __builtin_amdgcn_mfma_f32_16x16x32_bf16(
                    af[ks], bfr[ks][tn], acc[tn], 0, 0, 0);

        // C/D layout: col = lane&15, row = quad*4 + reg
        #pragma unroll
        for (int tn = 0; tn < 4; ++tn) {
            int col = ch * 64 + tn * 16 + lr;
            float bv_ = bcol[tn];
            int nb = row0 + quad * 4;
            #pragma unroll
            for (int r = 0; r < 4; ++r) {
                int node = nb + r;
                float val = acc[tn][r] + bv_;
                if (mat == 0)
                    qb[(size_t)node * DD + col] = f2bf(val);
                else if (mat == 1)
                    kvb[(size_t)node * KVROW + col] = f2fp8(val);
                else if (mat == 2)
                    *(unsigned short*)(kvb + (size_t)node * KVROW + 128 + col * 2) = f2bf(val);
                else
                    sb[(size_t)node * DD + col] = f2bf(val);
            }
        }
    }
}

// ---------------- fused online-softmax attention ----------------------------
// k fp8 (8 B/lane), v bf16 (16 B/lane); 2-deep pipeline + index prefetch.

__global__ __launch_bounds__(256) void attn_kernel(
    const unsigned short* __restrict__ qb, const unsigned char* __restrict__ kvb,
    const unsigned short* __restrict__ sb,
    const int* __restrict__ indptr, const int* __restrict__ esrc,
    unsigned short* __restrict__ hout, int n) {
    int node = (int)((blockIdx.x * blockDim.x + threadIdx.x) >> 6);
    int lane = threadIdx.x & 63;
    if (node >= n) return;
    int g = lane >> 4, j = lane & 15;

    u16x8 q8 = *(const u16x8*)(qb + (size_t)node * DD + j * 8);
    float qf[8];
    #pragma unroll
    for (int c = 0; c < 8; ++c) qf[c] = bf2f(q8[c]);

    int beg = indptr[node], end = indptr[node + 1];

    float m = -3.0e38f, den = 0.f;
    float acc[8];
    #pragma unroll
    for (int c = 0; c < 8; ++c) acc[c] = 0.f;

    int e = beg + g;
    if (e < end) {
        int sidx = esrc[e];
        int en = e + 4;
        int sn = (en < end) ? esrc[en] : 0;          // index 1 ahead (resident)
        const unsigned char* row = kvb + (size_t)sidx * KVROW;
        uint2 kk = *(const uint2*)(row + j * 8);
        u16x8 v8 = *(const u16x8*)(row + 128 + j * 16);
        for (;;) {
            bool haven = en < end;
            int en2 = en + 4;
            int sn2 = (en2 < end) ? esrc[en2] : 0;   // index 2 ahead (loading)
            uint2 kkn; u16x8 v8n;
            if (haven) {
                const unsigned char* p = kvb + (size_t)sn * KVROW;
                kkn = *(const uint2*)(p + j * 8);
                v8n = *(const u16x8*)(p + 128 + j * 16);
            }
            f32x2 k01 = __builtin_amdgcn_cvt_pk_f32_fp8(kk.x, false);
            f32x2 k23 = __builtin_amdgcn_cvt_pk_f32_fp8(kk.x, true);
            f32x2 k45 = __builtin_amdgcn_cvt_pk_f32_fp8(kk.y, false);
            f32x2 k67 = __builtin_amdgcn_cvt_pk_f32_fp8(kk.y, true);
            float p_;
            p_ = qf[0] * k01.x;
            p_ = fmaf(qf[1], k01.y, p_);
            p_ = fmaf(qf[2], k23.x, p_);
            p_ = fmaf(qf[3], k23.y, p_);
            p_ = fmaf(qf[4], k45.x, p_);
            p_ = fmaf(qf[5], k45.y, p_);
            p_ = fmaf(qf[6], k67.x, p_);
            p_ = fmaf(qf[7], k67.y, p_);
            p_ += __shfl_xor(p_, 8);
            p_ += __shfl_xor(p_, 4);
            p_ += __shfl_xor(p_, 2);
            p_ += __shfl_xor(p_, 1);
            float score = p_ * 0.088388347648318447f;   // 1/sqrt(128)
            float mn = fmaxf(m, score);
            float scale = __expf(m - mn);
            float pe = __expf(score - mn);
            den = den * scale + pe;
            #pragma unroll
            for (int c = 0; c < 8; ++c)
                acc[c] = fmaf(acc[c], scale, pe * bf2f(v8[c]));
            m = mn;
            if (!haven) break;
            en = en2; sn = sn2; kk = kkn; v8 = v8n;
        }
    }

    float mo = __shfl_xor(m, 16);
    float m2 = fmaxf(m, mo);
    mo = __shfl_xor(m2, 32);
    float mf = fmaxf(m2, mo);
    float sc = __expf(m - mf);
    den *= sc;
    den += __shfl_xor(den, 16);
    den += __shfl_xor(den, 32);
    #pragma unroll
    for (int c = 0; c < 8; ++c) {
        float a = acc[c] * sc;
        a += __shfl_xor(a, 16);
        a += __shfl_xor(a, 32);
        acc[c] = a;
    }
    float inv = den > 0.f ? 1.0f / den : 0.f;
    if (g == 0) {
        u16x8 s8 = *(const u16x8*)(sb + (size_t)node * DD + j * 8);
        u16x8 o8;
        #pragma unroll
        for (int c = 0; c < 8; ++c)
            o8[c] = f2bf(fmaxf(fmaf(acc[c], inv, bf2f(s8[c])), 0.f));
        *(u16x8*)(hout + (size_t)node * DD + j * 8) = o8;
    }
}

// ---------------- global mean pool (h bf16): segmented running sum ----------

__global__ __launch_bounds__(128) void pool_kernel(const unsigned short* __restrict__ h,
                                                   const int* __restrict__ batch,
                                                   float* __restrict__ gsum,
                                                   float* __restrict__ gcnt, int n) {
    __shared__ int bsh[PCHUNK];
    int t = threadIdx.x;
    int node0 = blockIdx.x * PCHUNK;
    int nnodes = min(PCHUNK, n - node0);
    if (t < nnodes) bsh[t] = batch[node0 + t];
    __syncthreads();

    int cur = bsh[0];
    float acc = 0.f;
    int cnt = 0;
    for (int j = 0; j < nnodes; ++j) {
        int g = bsh[j];
        float val = bf2f(h[(size_t)(node0 + j) * DD + t]);
        if (g != cur) {
            atomicAdd(&gsum[cur * DD + t], acc);
            if (t == 0) atomicAdd(&gcnt[cur], (float)cnt);
            acc = 0.f; cnt = 0; cur = g;
        }
        acc += val; ++cnt;
    }
    if (cnt > 0) {
        atomicAdd(&gsum[cur * DD + t], acc);
        if (t == 0) atomicAdd(&gcnt[cur], (float)cnt);
    }
}

// ---------------- FC + log_softmax ----------------

__global__ __launch_bounds__(64) void head_kernel(
    const float* __restrict__ gsum, const float* __restrict__ gcnt,
    const float* __restrict__ wfc, const float* __restrict__ bfc,
    float* __restrict__ out) {
    int g = blockIdx.x;
    int lane = threadIdx.x;
    float cnt = fmaxf(gcnt[g], 1.0f);
    float inv = 1.0f / cnt;
    float p0 = gsum[g * DD + lane] * inv;
    float p1 = gsum[g * DD + lane + 64] * inv;
    __shared__ float logits[NCLS];
    for (int c = 0; c < NCLS; ++c) {
        float partial = p0 * wfc[lane * NCLS + c] + p1 * wfc[(lane + 64) * NCLS + c];
        partial += __shfl_xor(partial, 32);
        partial += __shfl_xor(partial, 16);
        partial += __shfl_xor(partial, 8);
        partial += __shfl_xor(partial, 4);
        partial += __shfl_xor(partial, 2);
        partial += __shfl_xor(partial, 1);
        if (lane == 0) logits[c] = partial + bfc[c];
    }
    __syncthreads();
    if (lane == 0) {
        float mx = logits[0];
        for (int c = 1; c < NCLS; ++c) mx = fmaxf(mx, logits[c]);
        float sum = 0.f;
        for (int c = 0; c < NCLS; ++c) sum += expf(logits[c] - mx);
        float lse = mx + logf(sum);
        for (int c = 0; c < NCLS; ++c) out[g * NCLS + c] = logits[c] - lse;
    }
}

// ---------------- launch ----------------

extern "C" void kernel_launch(void* const* d_in, const int* in_sizes, int n_in,
                              void* d_out, int out_size, void* d_ws, size_t ws_size,
                              hipStream_t stream) {
    const float* x     = (const float*)d_in[0];
    const int*   ei    = (const int*)d_in[1];
    const int*   batch = (const int*)d_in[2];
    const float* Wq = (const float*)d_in[3];
    const float* bq = (const float*)d_in[4];
    const float* Wk = (const float*)d_in[5];
    const float* bk = (const float*)d_in[6];
    const float* Wv = (const float*)d_in[7];
    const float* bv = (const float*)d_in[8];
    const float* Ws = (const float*)d_in[9];
    const float* bs = (const float*)d_in[10];
    const float* Wfc = (const float*)d_in[11];
    const float* bfc = (const float*)d_in[12];
    float* out = (float*)d_out;

    const size_t ND = (size_t)NN * DD;
    unsigned short* hbuf = (unsigned short*)d_ws;
    unsigned short* qb  = hbuf + ND;
    unsigned short* sb  = qb + ND;
    unsigned char*  kvb = (unsigned char*)(sb + ND);    // [NN][384]: fp8 k | bf16 v
    unsigned short* wt  = (unsigned short*)(kvb + (size_t)NN * KVROW);
    int* bucketcnt = (int*)(wt + 2 * 4 * 16384);        // [256]
    int* indptr    = bucketcnt + 256;                   // [NN+1]
    int* esrc      = indptr + NN + 1;                   // [EE]
    int2* bedge    = (int2*)(esrc + EE);                // [NBUK*BSTRIDE]
    float* gsum = (float*)(bedge + NBUK * BSTRIDE);
    float* gcnt = gsum + GG * DD;

    const int* src = ei;
    const int* dst = ei + EE;

    prep_kernel<<<256, 256, 0, stream>>>(Wq, Wk, Wv, Ws, wt, bucketcnt, gsum);
    bucket_kernel<<<256, 1024, 0, stream>>>(src, dst, bucketcnt, bedge);
    bsort_kernel<<<NBUK, 1024, 0, stream>>>(bucketcnt, bedge, indptr, esrc);

    for (int l = 0; l < 2; ++l) {
        size_t bo = (size_t)l * DD;
        const unsigned short* wtl = wt + (size_t)l * 4 * 16384;
        if (l == 0)
            gemm_mfma<false><<<512, 256, 0, stream>>>(
                (const void*)x, wtl, bq + bo, bk + bo, bv + bo, bs + bo,
                qb, kvb, sb);
        else
            gemm_mfma<true><<<512, 256, 0, stream>>>(
                (const void*)hbuf, wtl, bq + bo, bk + bo, bv + bo, bs + bo,
                qb, kvb, sb);
        attn_kernel<<<(NN + 3) / 4, 256, 0, stream>>>(
            qb, kvb, sb, indptr, esrc, hbuf, NN);
    }

    pool_kernel<<<(NN + PCHUNK - 1) / PCHUNK, 128, 0, stream>>>(hbuf, batch, gsum, gcnt, NN);
    head_kernel<<<GG, 64, 0, stream>>>(gsum, gcnt, Wfc, bfc, out);
}

// Round 16
// 283.508 us; speedup vs baseline: 1.1180x; 1.1180x over previous
//
#include <hip/hip_runtime.h>
#include <math.h>

#define NN 50000
#define EE 600000
#define DD 128
#define GG 64
#define NCLS 10
#define PCHUNK 128
#define NTILE (NN / 16)            // 3125 row-tiles, exact
#define NBUK 196                   // buckets of 256 dst nodes (dst>>8)
#define BSTRIDE 4096               // slots per bucket (mean 3072, sigma 55)
#define EPB ((EE + 255) / 256)     // 2344 edges per pass-1 block

typedef __attribute__((ext_vector_type(8))) __bf16 bf16x8;
typedef __attribute__((ext_vector_type(8))) unsigned short u16x8;
typedef __attribute__((ext_vector_type(4))) float f32x4;

__device__ __forceinline__ unsigned short f2bf(float f) {
    unsigned int u = __float_as_uint(f);
    u += 0x7fff + ((u >> 16) & 1);     // round-to-nearest-even
    return (unsigned short)(u >> 16);
}

__device__ __forceinline__ float bf2f(unsigned short h) {
    return __uint_as_float(((unsigned int)h) << 16);
}

// dword-wise bf16 pair unpack: 1 VALU op per element (vs 2 for extract+shl)
__device__ __forceinline__ float lo16(unsigned int u) { return __uint_as_float(u << 16); }
__device__ __forceinline__ float hi16(unsigned int u) { return __uint_as_float(u & 0xffff0000u); }

// ---------------- fused prep: zero bucketcnt/gsum + wt convert --------------

__global__ __launch_bounds__(256) void prep_kernel(
    const float* __restrict__ wq, const float* __restrict__ wk,
    const float* __restrict__ wv, const float* __restrict__ ws,
    unsigned short* __restrict__ wt,
    int* __restrict__ bucketcnt, float* __restrict__ gsum) {
    int tid = blockIdx.x * 256 + threadIdx.x;
    int TOT = gridDim.x * 256;
    if (tid < 256) bucketcnt[tid] = 0;
    for (int i = tid; i < GG * DD + GG; i += TOT) gsum[i] = 0.f;
    for (int i = tid; i < 2 * 4 * 16384; i += TOT) {
        int k = i & 127;
        int n = (i >> 7) & 127;
        int lm = i >> 14;
        int l = lm >> 2, m = lm & 3;
        const float* w = (m == 0) ? wq : (m == 1) ? wk : (m == 2) ? wv : ws;
        wt[i] = f2bf(w[l * 16384 + k * 128 + n]);
    }
}

// ---------------- CSR pass 1: bucket by dst>>8 ------------------------------

__global__ __launch_bounds__(1024) void bucket_kernel(
    const int* __restrict__ src, const int* __restrict__ dst,
    int* __restrict__ bucketcnt, int2* __restrict__ bedge) {
    __shared__ int hist[256];
    __shared__ int base[256];
    int t = threadIdx.x;
    if (t < 256) hist[t] = 0;
    __syncthreads();
    int e0 = blockIdx.x * EPB;
    int eend = min(e0 + EPB, EE);

    int b0 = -1, b1 = -1, b2 = -1;
    int sl0 = 0, sl1 = 0, sl2 = 0;
    int s0 = 0, s1 = 0, s2 = 0, d0 = 0, d1 = 0, d2 = 0;
    int i = e0 + t;
    if (i < eend) { d0 = dst[i]; s0 = src[i]; b0 = d0 >> 8; sl0 = atomicAdd(&hist[b0], 1); }
    i += 1024;
    if (i < eend) { d1 = dst[i]; s1 = src[i]; b1 = d1 >> 8; sl1 = atomicAdd(&hist[b1], 1); }
    i += 1024;
    if (i < eend) { d2 = dst[i]; s2 = src[i]; b2 = d2 >> 8; sl2 = atomicAdd(&hist[b2], 1); }
    __syncthreads();

    if (t < 256) {
        int h = hist[t];
        base[t] = h ? atomicAdd(&bucketcnt[t], h) : 0;
    }
    __syncthreads();

    if (b0 >= 0) bedge[b0 * BSTRIDE + base[b0] + sl0] = make_int2(s0, d0);
    if (b1 >= 0) bedge[b1 * BSTRIDE + base[b1] + sl1] = make_int2(s1, d1);
    if (b2 >= 0) bedge[b2 * BSTRIDE + base[b2] + sl2] = make_int2(s2, d2);
}

// ---------------- CSR pass 2: per-bucket node sort -> indptr + esrc ---------

__global__ __launch_bounds__(1024) void bsort_kernel(
    const int* __restrict__ bucketcnt, const int2* __restrict__ bedge,
    int* __restrict__ indptr, int* __restrict__ esrc) {
    __shared__ int buf[256];
    __shared__ int cur[256];
    int b = blockIdx.x;
    int t = threadIdx.x;

    if (t < 256) buf[t] = (t < NBUK) ? bucketcnt[t] : 0;
    __syncthreads();
    if (t < 64) {
        int carry = 0;
        #pragma unroll
        for (int c = 0; c < 4; ++c) {
            int v = buf[c * 64 + t];
            int x = v;
            #pragma unroll
            for (int off = 1; off < 64; off <<= 1) {
                int y = __shfl_up(x, off);
                if (t >= off) x += y;
            }
            cur[c * 64 + t] = carry + x - v;
            carry += __shfl(x, 63);
        }
    }
    __syncthreads();
    int count = buf[b];
    int bstart = cur[b];
    int node0 = b << 8;
    int nn = min(256, NN - node0);
    if (b == 0 && t == 0) indptr[NN] = EE;
    __syncthreads();
    if (t < 256) buf[t] = 0;
    __syncthreads();

    const int2* be = bedge + (size_t)b * BSTRIDE;
    for (int i2 = t; i2 < count; i2 += 1024)
        atomicAdd(&buf[be[i2].y - node0], 1);
    __syncthreads();

    if (t < 64) {
        int carry = 0;
        #pragma unroll
        for (int c = 0; c < 4; ++c) {
            int v = buf[c * 64 + t];
            int x = v;
            #pragma unroll
            for (int off = 1; off < 64; off <<= 1) {
                int y = __shfl_up(x, off);
                if (t >= off) x += y;
            }
            cur[c * 64 + t] = carry + x - v;
            carry += __shfl(x, 63);
        }
    }
    __syncthreads();
    if (t < nn) indptr[node0 + t] = bstart + cur[t];
    __syncthreads();

    for (int i2 = t; i2 < count; i2 += 1024) {
        int2 e = be[i2];
        int slot = atomicAdd(&cur[e.y - node0], 1);
        esrc[bstart + slot] = e.x;
    }
}

// ---------------- persistent-wave LDS-free bf16 MFMA GEMM (R10 winner) -----
// kv row: [128 bf16 k | 128 bf16 v] = 512 B (R15 fp8-k byte stores caused RFO
// blowup - keep 2-byte-aligned stores in the epilogue).

template <bool IN_BF16>
__global__ __launch_bounds__(256, 4) void gemm_mfma(
    const void* __restrict__ xin,
    const unsigned short* __restrict__ wt,      // [4][128][128] bf16, n-major
    const float* __restrict__ bq, const float* __restrict__ bk,
    const float* __restrict__ bv, const float* __restrict__ bs,
    unsigned short* __restrict__ qb, unsigned short* __restrict__ kvb,
    unsigned short* __restrict__ sb) {
    int gw = blockIdx.x * 4 + (threadIdx.x >> 6);   // 0..2047
    int lane = threadIdx.x & 63;
    int mat = (gw >> 1) & 3;
    int ch = gw & 1;
    int wseq = gw >> 3;                              // 0..255
    int lr = lane & 15, quad = lane >> 4;

    const unsigned short* wm_ = wt + mat * 16384;
    const float* bias = (mat == 0) ? bq : (mat == 1) ? bk : (mat == 2) ? bv : bs;
    unsigned short* outp; int ostride, ooff;
    if (mat == 0)      { outp = qb;  ostride = 128; ooff = 0; }
    else if (mat == 1) { outp = kvb; ostride = 256; ooff = 0; }
    else if (mat == 2) { outp = kvb; ostride = 256; ooff = 128; }
    else               { outp = sb;  ostride = 128; ooff = 0; }

    bf16x8 bfr[4][4];
    #pragma unroll
    for (int ks = 0; ks < 4; ++ks)
        #pragma unroll
        for (int tn = 0; tn < 4; ++tn)
            bfr[ks][tn] = *(const bf16x8*)(wm_ + (ch * 64 + tn * 16 + lr) * 128
                                               + ks * 32 + quad * 8);
    float bcol[4];
    #pragma unroll
    for (int tn = 0; tn < 4; ++tn) bcol[tn] = bias[ch * 64 + tn * 16 + lr];

    for (int tile = wseq; tile < NTILE; tile += 256) {
        int row0 = tile * 16;
        bf16x8 af[4];
        #pragma unroll
        for (int ks = 0; ks < 4; ++ks) {
            if (IN_BF16) {
                af[ks] = *(const bf16x8*)((const unsigned short*)xin
                             + (size_t)(row0 + lr) * DD + ks * 32 + quad * 8);
            } else {
                const float* p = (const float*)xin
                                 + (size_t)(row0 + lr) * DD + ks * 32 + quad * 8;
                float4 f0 = *(const float4*)p;
                float4 f1 = *(const float4*)(p + 4);
                u16x8 a8;
                a8[0] = f2bf(f0.x); a8[1] = f2bf(f0.y); a8[2] = f2bf(f0.z); a8[3] = f2bf(f0.w);
                a8[4] = f2bf(f1.x); a8[5] = f2bf(f1.y); a8[6] = f2bf(f1.z); a8[7] = f2bf(f1.w);
                af[ks] = *(bf16x8*)&a8;
            }
        }

        f32x4 acc[4];
        #pragma unroll
        for (int tn = 0; tn < 4; ++tn) acc[tn] = (f32x4){0.f, 0.f, 0.f, 0.f};
        #pragma unroll
        for (int ks = 0; ks < 4; ++ks)
            #pragma unroll
            for (int tn = 0; tn < 4; ++tn)
                acc[tn] = __builtin_amdgcn_mfma_f32_16x16x32_bf16(
                    af[ks], bfr[ks][tn], acc[tn], 0, 0, 0);

        // C/D layout: col = lane&15, row = quad*4 + reg
        #pragma unroll
        for (int tn = 0; tn < 4; ++tn) {
            int col = ch * 64 + tn * 16 + lr;
            int nb = row0 + quad * 4;
            #pragma unroll
            for (int r = 0; r < 4; ++r)
                outp[(size_t)(nb + r) * ostride + ooff + col] = f2bf(acc[tn][r] + bcol[tn]);
        }
    }
}

// ---------------- fused online-softmax attention ----------------------------
// kv interleaved; 2-deep kv pipeline + esrc index prefetch; dword-wise bf16
// unpack (u<<16 / u&0xffff0000) halves unpack VALU vs per-element bf2f.

__global__ __launch_bounds__(256) void attn_kernel(
    const unsigned short* __restrict__ qb, const unsigned short* __restrict__ kvb,
    const unsigned short* __restrict__ sb,
    const int* __restrict__ indptr, const int* __restrict__ esrc,
    unsigned short* __restrict__ hout, int n) {
    int node = (int)((blockIdx.x * blockDim.x + threadIdx.x) >> 6);
    int lane = threadIdx.x & 63;
    if (node >= n) return;
    int g = lane >> 4, j = lane & 15;

    u16x8 q8 = *(const u16x8*)(qb + (size_t)node * DD + j * 8);
    float qf[8];
    #pragma unroll
    for (int c = 0; c < 8; ++c) qf[c] = bf2f(q8[c]);

    int beg = indptr[node], end = indptr[node + 1];

    float m = -3.0e38f, den = 0.f;
    float acc[8];
    #pragma unroll
    for (int c = 0; c < 8; ++c) acc[c] = 0.f;

    int e = beg + g;
    if (e < end) {
        int sidx = esrc[e];
        int en = e + 4;
        int sn = (en < end) ? esrc[en] : 0;          // index 1 ahead (resident)
        const unsigned short* p0 = kvb + (size_t)sidx * 256 + j * 8;
        uint4 kk = *(const uint4*)p0;
        uint4 vv = *(const uint4*)(p0 + 128);
        for (;;) {
            bool haven = en < end;
            int en2 = en + 4;
            int sn2 = (en2 < end) ? esrc[en2] : 0;   // index 2 ahead (loading)
            uint4 kkn, vvn;
            if (haven) {
                const unsigned short* p = kvb + (size_t)sn * 256 + j * 8;
                kkn = *(const uint4*)p;
                vvn = *(const uint4*)(p + 128);
            }
            float p_;
            p_ = qf[0] * lo16(kk.x);
            p_ = fmaf(qf[1], hi16(kk.x), p_);
            p_ = fmaf(qf[2], lo16(kk.y), p_);
            p_ = fmaf(qf[3], hi16(kk.y), p_);
            p_ = fmaf(qf[4], lo16(kk.z), p_);
            p_ = fmaf(qf[5], hi16(kk.z), p_);
            p_ = fmaf(qf[6], lo16(kk.w), p_);
            p_ = fmaf(qf[7], hi16(kk.w), p_);
            p_ += __shfl_xor(p_, 8);
            p_ += __shfl_xor(p_, 4);
            p_ += __shfl_xor(p_, 2);
            p_ += __shfl_xor(p_, 1);
            float score = p_ * 0.088388347648318447f;   // 1/sqrt(128)
            float mn = fmaxf(m, score);
            float scale = __expf(m - mn);
            float pe = __expf(score - mn);
            den = den * scale + pe;
            acc[0] = fmaf(acc[0], scale, pe * lo16(vv.x));
            acc[1] = fmaf(acc[1], scale, pe * hi16(vv.x));
            acc[2] = fmaf(acc[2], scale, pe * lo16(vv.y));
            acc[3] = fmaf(acc[3], scale, pe * hi16(vv.y));
            acc[4] = fmaf(acc[4], scale, pe * lo16(vv.z));
            acc[5] = fmaf(acc[5], scale, pe * hi16(vv.z));
            acc[6] = fmaf(acc[6], scale, pe * lo16(vv.w));
            acc[7] = fmaf(acc[7], scale, pe * hi16(vv.w));
            m = mn;
            if (!haven) break;
            en = en2; sn = sn2; kk = kkn; vv = vvn;
        }
    }

    float mo = __shfl_xor(m, 16);
    float m2 = fmaxf(m, mo);
    mo = __shfl_xor(m2, 32);
    float mf = fmaxf(m2, mo);
    float sc = __expf(m - mf);
    den *= sc;
    den += __shfl_xor(den, 16);
    den += __shfl_xor(den, 32);
    #pragma unroll
    for (int c = 0; c < 8; ++c) {
        float a = acc[c] * sc;
        a += __shfl_xor(a, 16);
        a += __shfl_xor(a, 32);
        acc[c] = a;
    }
    float inv = den > 0.f ? 1.0f / den : 0.f;
    if (g == 0) {
        u16x8 s8 = *(const u16x8*)(sb + (size_t)node * DD + j * 8);
        u16x8 o8;
        #pragma unroll
        for (int c = 0; c < 8; ++c)
            o8[c] = f2bf(fmaxf(fmaf(acc[c], inv, bf2f(s8[c])), 0.f));
        *(u16x8*)(hout + (size_t)node * DD + j * 8) = o8;
    }
}

// ---------------- global mean pool (h bf16): segmented running sum ----------

__global__ __launch_bounds__(128) void pool_kernel(const unsigned short* __restrict__ h,
                                                   const int* __restrict__ batch,
                                                   float* __restrict__ gsum,
                                                   float* __restrict__ gcnt, int n) {
    __shared__ int bsh[PCHUNK];
    int t = threadIdx.x;
    int node0 = blockIdx.x * PCHUNK;
    int nnodes = min(PCHUNK, n - node0);
    if (t < nnodes) bsh[t] = batch[node0 + t];
    __syncthreads();

    int cur = bsh[0];
    float acc = 0.f;
    int cnt = 0;
    for (int j = 0; j < nnodes; ++j) {
        int g = bsh[j];
        float val = bf2f(h[(size_t)(node0 + j) * DD + t]);
        if (g != cur) {
            atomicAdd(&gsum[cur * DD + t], acc);
            if (t == 0) atomicAdd(&gcnt[cur], (float)cnt);
            acc = 0.f; cnt = 0; cur = g;
        }
        acc += val; ++cnt;
    }
    if (cnt > 0) {
        atomicAdd(&gsum[cur * DD + t], acc);
        if (t == 0) atomicAdd(&gcnt[cur], (float)cnt);
    }
}

// ---------------- FC + log_softmax ----------------

__global__ __launch_bounds__(64) void head_kernel(
    const float* __restrict__ gsum, const float* __restrict__ gcnt,
    const float* __restrict__ wfc, const float* __restrict__ bfc,
    float* __restrict__ out) {
    int g = blockIdx.x;
    int lane = threadIdx.x;
    float cnt = fmaxf(gcnt[g], 1.0f);
    float inv = 1.0f / cnt;
    float p0 = gsum[g * DD + lane] * inv;
    float p1 = gsum[g * DD + lane + 64] * inv;
    __shared__ float logits[NCLS];
    for (int c = 0; c < NCLS; ++c) {
        float partial = p0 * wfc[lane * NCLS + c] + p1 * wfc[(lane + 64) * NCLS + c];
        partial += __shfl_xor(partial, 32);
        partial += __shfl_xor(partial, 16);
        partial += __shfl_xor(partial, 8);
        partial += __shfl_xor(partial, 4);
        partial += __shfl_xor(partial, 2);
        partial += __shfl_xor(partial, 1);
        if (lane == 0) logits[c] = partial + bfc[c];
    }
    __syncthreads();
    if (lane == 0) {
        float mx = logits[0];
        for (int c = 1; c < NCLS; ++c) mx = fmaxf(mx, logits[c]);
        float sum = 0.f;
        for (int c = 0; c < NCLS; ++c) sum += expf(logits[c] - mx);
        float lse = mx + logf(sum);
        for (int c = 0; c < NCLS; ++c) out[g * NCLS + c] = logits[c] - lse;
    }
}

// ---------------- launch ----------------

extern "C" void kernel_launch(void* const* d_in, const int* in_sizes, int n_in,
                              void* d_out, int out_size, void* d_ws, size_t ws_size,
                              hipStream_t stream) {
    const float* x     = (const float*)d_in[0];
    const int*   ei    = (const int*)d_in[1];
    const int*   batch = (const int*)d_in[2];
    const float* Wq = (const float*)d_in[3];
    const float* bq = (const float*)d_in[4];
    const float* Wk = (const float*)d_in[5];
    const float* bk = (const float*)d_in[6];
    const float* Wv = (const float*)d_in[7];
    const float* bv = (const float*)d_in[8];
    const float* Ws = (const float*)d_in[9];
    const float* bs = (const float*)d_in[10];
    const float* Wfc = (const float*)d_in[11];
    const float* bfc = (const float*)d_in[12];
    float* out = (float*)d_out;

    const size_t ND = (size_t)NN * DD;
    unsigned short* hbuf = (unsigned short*)d_ws;   // all bf16
    unsigned short* qb  = hbuf + ND;
    unsigned short* sb  = qb + ND;
    unsigned short* kvb = sb + ND;                  // [NN][256]: k | v interleaved
    unsigned short* wt  = kvb + 2 * ND;             // [2][4][128][128] bf16
    int* bucketcnt = (int*)(wt + 2 * 4 * 16384);    // [256]
    int* indptr    = bucketcnt + 256;               // [NN+1]
    int* esrc      = indptr + NN + 1;               // [EE]
    int2* bedge    = (int2*)(esrc + EE);            // [NBUK*BSTRIDE]
    float* gsum = (float*)(bedge + NBUK * BSTRIDE);
    float* gcnt = gsum + GG * DD;

    const int* src = ei;
    const int* dst = ei + EE;

    prep_kernel<<<256, 256, 0, stream>>>(Wq, Wk, Wv, Ws, wt, bucketcnt, gsum);
    bucket_kernel<<<256, 1024, 0, stream>>>(src, dst, bucketcnt, bedge);
    bsort_kernel<<<NBUK, 1024, 0, stream>>>(bucketcnt, bedge, indptr, esrc);

    for (int l = 0; l < 2; ++l) {
        size_t bo = (size_t)l * DD;
        const unsigned short* wtl = wt + (size_t)l * 4 * 16384;
        if (l == 0)
            gemm_mfma<false><<<512, 256, 0, stream>>>(
                (const void*)x, wtl, bq + bo, bk + bo, bv + bo, bs + bo,
                qb, kvb, sb);
        else
            gemm_mfma<true><<<512, 256, 0, stream>>>(
                (const void*)hbuf, wtl, bq + bo, bk + bo, bv + bo, bs + bo,
                qb, kvb, sb);
        attn_kernel<<<(NN + 3) / 4, 256, 0, stream>>>(
            qb, kvb, sb, indptr, esrc, hbuf, NN);
    }

    pool_kernel<<<(NN + PCHUNK - 1) / PCHUNK, 128, 0, stream>>>(hbuf, batch, gsum, gcnt, NN);
    head_kernel<<<GG, 64, 0, stream>>>(gsum, gcnt, Wfc, bfc, out);
}

// Round 17
// 271.528 us; speedup vs baseline: 1.1673x; 1.0441x over previous
//
#include <hip/hip_runtime.h>
#include <math.h>

#define NN 50000
#define EE 600000
#define DD 128
#define GG 64
#define NCLS 10
#define PCHUNK 128
#define NTILE (NN / 16)            // 3125 row-tiles, exact
#define NBUK 196                   // buckets of 256 dst nodes (dst>>8)
#define BSTRIDE 4096               // slots per bucket (mean 3072, sigma 55)
#define EPB ((EE + 255) / 256)     // 2344 edges per pass-1 block

typedef __attribute__((ext_vector_type(8))) __bf16 bf16x8;
typedef __attribute__((ext_vector_type(8))) unsigned short u16x8;
typedef __attribute__((ext_vector_type(4))) float f32x4;
typedef __attribute__((ext_vector_type(2))) float f32x2;

__device__ __forceinline__ unsigned short f2bf(float f) {
    unsigned int u = __float_as_uint(f);
    u += 0x7fff + ((u >> 16) & 1);     // round-to-nearest-even
    return (unsigned short)(u >> 16);
}

__device__ __forceinline__ float bf2f(unsigned short h) {
    return __uint_as_float(((unsigned int)h) << 16);
}

// dword-wise bf16 pair unpack: 1 VALU op per element
__device__ __forceinline__ float lo16(unsigned int u) { return __uint_as_float(u << 16); }
__device__ __forceinline__ float hi16(unsigned int u) { return __uint_as_float(u & 0xffff0000u); }

// ---------------- fused prep: zero bucketcnt/gsum + wt convert --------------

__global__ __launch_bounds__(256) void prep_kernel(
    const float* __restrict__ wq, const float* __restrict__ wk,
    const float* __restrict__ wv, const float* __restrict__ ws,
    unsigned short* __restrict__ wt,
    int* __restrict__ bucketcnt, float* __restrict__ gsum) {
    int tid = blockIdx.x * 256 + threadIdx.x;
    int TOT = gridDim.x * 256;
    if (tid < 256) bucketcnt[tid] = 0;
    for (int i = tid; i < GG * DD + GG; i += TOT) gsum[i] = 0.f;
    for (int i = tid; i < 2 * 4 * 16384; i += TOT) {
        int k = i & 127;
        int n = (i >> 7) & 127;
        int lm = i >> 14;
        int l = lm >> 2, m = lm & 3;
        const float* w = (m == 0) ? wq : (m == 1) ? wk : (m == 2) ? wv : ws;
        wt[i] = f2bf(w[l * 16384 + k * 128 + n]);
    }
}

// ---------------- CSR pass 1: bucket by dst>>8 ------------------------------

__global__ __launch_bounds__(1024) void bucket_kernel(
    const int* __restrict__ src, const int* __restrict__ dst,
    int* __restrict__ bucketcnt, int2* __restrict__ bedge) {
    __shared__ int hist[256];
    __shared__ int base[256];
    int t = threadIdx.x;
    if (t < 256) hist[t] = 0;
    __syncthreads();
    int e0 = blockIdx.x * EPB;
    int eend = min(e0 + EPB, EE);

    int b0 = -1, b1 = -1, b2 = -1;
    int sl0 = 0, sl1 = 0, sl2 = 0;
    int s0 = 0, s1 = 0, s2 = 0, d0 = 0, d1 = 0, d2 = 0;
    int i = e0 + t;
    if (i < eend) { d0 = dst[i]; s0 = src[i]; b0 = d0 >> 8; sl0 = atomicAdd(&hist[b0], 1); }
    i += 1024;
    if (i < eend) { d1 = dst[i]; s1 = src[i]; b1 = d1 >> 8; sl1 = atomicAdd(&hist[b1], 1); }
    i += 1024;
    if (i < eend) { d2 = dst[i]; s2 = src[i]; b2 = d2 >> 8; sl2 = atomicAdd(&hist[b2], 1); }
    __syncthreads();

    if (t < 256) {
        int h = hist[t];
        base[t] = h ? atomicAdd(&bucketcnt[t], h) : 0;
    }
    __syncthreads();

    if (b0 >= 0) bedge[b0 * BSTRIDE + base[b0] + sl0] = make_int2(s0, d0);
    if (b1 >= 0) bedge[b1 * BSTRIDE + base[b1] + sl1] = make_int2(s1, d1);
    if (b2 >= 0) bedge[b2 * BSTRIDE + base[b2] + sl2] = make_int2(s2, d2);
}

// ---------------- CSR pass 2: per-bucket node sort -> indptr + esrc ---------

__global__ __launch_bounds__(1024) void bsort_kernel(
    const int* __restrict__ bucketcnt, const int2* __restrict__ bedge,
    int* __restrict__ indptr, int* __restrict__ esrc) {
    __shared__ int buf[256];
    __shared__ int cur[256];
    int b = blockIdx.x;
    int t = threadIdx.x;

    if (t < 256) buf[t] = (t < NBUK) ? bucketcnt[t] : 0;
    __syncthreads();
    if (t < 64) {
        int carry = 0;
        #pragma unroll
        for (int c = 0; c < 4; ++c) {
            int v = buf[c * 64 + t];
            int x = v;
            #pragma unroll
            for (int off = 1; off < 64; off <<= 1) {
                int y = __shfl_up(x, off);
                if (t >= off) x += y;
            }
            cur[c * 64 + t] = carry + x - v;
            carry += __shfl(x, 63);
        }
    }
    __syncthreads();
    int count = buf[b];
    int bstart = cur[b];
    int node0 = b << 8;
    int nn = min(256, NN - node0);
    if (b == 0 && t == 0) indptr[NN] = EE;
    __syncthreads();
    if (t < 256) buf[t] = 0;
    __syncthreads();

    const int2* be = bedge + (size_t)b * BSTRIDE;
    for (int i2 = t; i2 < count; i2 += 1024)
        atomicAdd(&buf[be[i2].y - node0], 1);
    __syncthreads();

    if (t < 64) {
        int carry = 0;
        #pragma unroll
        for (int c = 0; c < 4; ++c) {
            int v = buf[c * 64 + t];
            int x = v;
            #pragma unroll
            for (int off = 1; off < 64; off <<= 1) {
                int y = __shfl_up(x, off);
                if (t >= off) x += y;
            }
            cur[c * 64 + t] = carry + x - v;
            carry += __shfl(x, 63);
        }
    }
    __syncthreads();
    if (t < nn) indptr[node0 + t] = bstart + cur[t];
    __syncthreads();

    for (int i2 = t; i2 < count; i2 += 1024) {
        int2 e = be[i2];
        int slot = atomicAdd(&cur[e.y - node0], 1);
        esrc[bstart + slot] = e.x;
    }
}

// ---------------- persistent-wave LDS-free bf16 MFMA GEMM (R10 winner) -----
// Epilogue unchanged from R16: 2-byte aligned bf16 stores only (R15 lesson:
// byte-granular epilogue stores cause RFO fetch blowup).

template <bool IN_BF16>
__global__ __launch_bounds__(256, 4) void gemm_mfma(
    const void* __restrict__ xin,
    const unsigned short* __restrict__ wt,      // [4][128][128] bf16, n-major
    const float* __restrict__ bq, const float* __restrict__ bk,
    const float* __restrict__ bv, const float* __restrict__ bs,
    unsigned short* __restrict__ qb, unsigned short* __restrict__ kvb,
    unsigned short* __restrict__ sb) {
    int gw = blockIdx.x * 4 + (threadIdx.x >> 6);   // 0..2047
    int lane = threadIdx.x & 63;
    int mat = (gw >> 1) & 3;
    int ch = gw & 1;
    int wseq = gw >> 3;                              // 0..255
    int lr = lane & 15, quad = lane >> 4;

    const unsigned short* wm_ = wt + mat * 16384;
    const float* bias = (mat == 0) ? bq : (mat == 1) ? bk : (mat == 2) ? bv : bs;
    unsigned short* outp; int ostride, ooff;
    if (mat == 0)      { outp = qb;  ostride = 128; ooff = 0; }
    else if (mat == 1) { outp = kvb; ostride = 256; ooff = 0; }
    else if (mat == 2) { outp = kvb; ostride = 256; ooff = 128; }
    else               { outp = sb;  ostride = 128; ooff = 0; }

    bf16x8 bfr[4][4];
    #pragma unroll
    for (int ks = 0; ks < 4; ++ks)
        #pragma unroll
        for (int tn = 0; tn < 4; ++tn)
            bfr[ks][tn] = *(const bf16x8*)(wm_ + (ch * 64 + tn * 16 + lr) * 128
                                               + ks * 32 + quad * 8);
    float bcol[4];
    #pragma unroll
    for (int tn = 0; tn < 4; ++tn) bcol[tn] = bias[ch * 64 + tn * 16 + lr];

    for (int tile = wseq; tile < NTILE; tile += 256) {
        int row0 = tile * 16;
        bf16x8 af[4];
        #pragma unroll
        for (int ks = 0; ks < 4; ++ks) {
            if (IN_BF16) {
                af[ks] = *(const bf16x8*)((const unsigned short*)xin
                             + (size_t)(row0 + lr) * DD + ks * 32 + quad * 8);
            } else {
                const float* p = (const float*)xin
                                 + (size_t)(row0 + lr) * DD + ks * 32 + quad * 8;
                float4 f0 = *(const float4*)p;
                float4 f1 = *(const float4*)(p + 4);
                u16x8 a8;
                a8[0] = f2bf(f0.x); a8[1] = f2bf(f0.y); a8[2] = f2bf(f0.z); a8[3] = f2bf(f0.w);
                a8[4] = f2bf(f1.x); a8[5] = f2bf(f1.y); a8[6] = f2bf(f1.z); a8[7] = f2bf(f1.w);
                af[ks] = *(bf16x8*)&a8;
            }
        }

        f32x4 acc[4];
        #pragma unroll
        for (int tn = 0; tn < 4; ++tn) acc[tn] = (f32x4){0.f, 0.f, 0.f, 0.f};
        #pragma unroll
        for (int ks = 0; ks < 4; ++ks)
            #pragma unroll
            for (int tn = 0; tn < 4; ++tn)
                acc[tn] = __builtin_amdgcn_mfma_f32_16x16x32_bf16(
                    af[ks], bfr[ks][tn], acc[tn], 0, 0, 0);

        // C/D layout: col = lane&15, row = quad*4 + reg
        #pragma unroll
        for (int tn = 0; tn < 4; ++tn) {
            int col = ch * 64 + tn * 16 + lr;
            int nb = row0 + quad * 4;
            #pragma unroll
            for (int r = 0; r < 4; ++r)
                outp[(size_t)(nb + r) * ostride + ooff + col] = f2bf(acc[tn][r] + bcol[tn]);
        }
    }
}

// ---------------- kv bf16 -> packed fp8 convert (coalesced, no RFO) ---------
// out row (256 B): 16 chunks of 16 B; chunk j = [k ch 8j..8j+8 fp8 | v ch 8j..8j+8 fp8]
// -> attention gathers ONE uint4 per edge per lane.

__global__ __launch_bounds__(256) void kv8_kernel(
    const unsigned short* __restrict__ kvb, unsigned char* __restrict__ kv8) {
    int idx = blockIdx.x * 256 + threadIdx.x;       // chunk id: node*16 + j
    int node = idx >> 4, j = idx & 15;
    const unsigned short* base = kvb + (size_t)node * 256;
    uint4 kin = *(const uint4*)(base + j * 8);
    uint4 vin = *(const uint4*)(base + 128 + j * 8);
    unsigned int w0 = __builtin_amdgcn_cvt_pk_fp8_f32(lo16(kin.x), hi16(kin.x), 0, false);
    w0 = __builtin_amdgcn_cvt_pk_fp8_f32(lo16(kin.y), hi16(kin.y), w0, true);
    unsigned int w1 = __builtin_amdgcn_cvt_pk_fp8_f32(lo16(kin.z), hi16(kin.z), 0, false);
    w1 = __builtin_amdgcn_cvt_pk_fp8_f32(lo16(kin.w), hi16(kin.w), w1, true);
    unsigned int w2 = __builtin_amdgcn_cvt_pk_fp8_f32(lo16(vin.x), hi16(vin.x), 0, false);
    w2 = __builtin_amdgcn_cvt_pk_fp8_f32(lo16(vin.y), hi16(vin.y), w2, true);
    unsigned int w3 = __builtin_amdgcn_cvt_pk_fp8_f32(lo16(vin.z), hi16(vin.z), 0, false);
    w3 = __builtin_amdgcn_cvt_pk_fp8_f32(lo16(vin.w), hi16(vin.w), w3, true);
    *(uint4*)(kv8 + (size_t)idx * 16) = make_uint4(w0, w1, w2, w3);
}

// ---------------- fused online-softmax attention (fp8 kv, 1 gather/edge) ----

__global__ __launch_bounds__(256) void attn_kernel(
    const unsigned short* __restrict__ qb, const unsigned char* __restrict__ kv8,
    const unsigned short* __restrict__ sb,
    const int* __restrict__ indptr, const int* __restrict__ esrc,
    unsigned short* __restrict__ hout, int n) {
    int node = (int)((blockIdx.x * blockDim.x + threadIdx.x) >> 6);
    int lane = threadIdx.x & 63;
    if (node >= n) return;
    int g = lane >> 4, j = lane & 15;

    u16x8 q8 = *(const u16x8*)(qb + (size_t)node * DD + j * 8);
    float qf[8];
    #pragma unroll
    for (int c = 0; c < 8; ++c) qf[c] = bf2f(q8[c]);

    int beg = indptr[node], end = indptr[node + 1];

    float m = -3.0e38f, den = 0.f;
    float acc[8];
    #pragma unroll
    for (int c = 0; c < 8; ++c) acc[c] = 0.f;

    int e = beg + g;
    if (e < end) {
        int sidx = esrc[e];
        int en = e + 4;
        int sn = (en < end) ? esrc[en] : 0;          // index 1 ahead (resident)
        uint4 kv = *(const uint4*)(kv8 + (size_t)sidx * 256 + j * 16);
        for (;;) {
            bool haven = en < end;
            int en2 = en + 4;
            int sn2 = (en2 < end) ? esrc[en2] : 0;   // index 2 ahead (loading)
            uint4 kvn;
            if (haven)
                kvn = *(const uint4*)(kv8 + (size_t)sn * 256 + j * 16);
            f32x2 k01 = __builtin_amdgcn_cvt_pk_f32_fp8(kv.x, false);
            f32x2 k23 = __builtin_amdgcn_cvt_pk_f32_fp8(kv.x, true);
            f32x2 k45 = __builtin_amdgcn_cvt_pk_f32_fp8(kv.y, false);
            f32x2 k67 = __builtin_amdgcn_cvt_pk_f32_fp8(kv.y, true);
            float p_;
            p_ = qf[0] * k01.x;
            p_ = fmaf(qf[1], k01.y, p_);
            p_ = fmaf(qf[2], k23.x, p_);
            p_ = fmaf(qf[3], k23.y, p_);
            p_ = fmaf(qf[4], k45.x, p_);
            p_ = fmaf(qf[5], k45.y, p_);
            p_ = fmaf(qf[6], k67.x, p_);
            p_ = fmaf(qf[7], k67.y, p_);
            p_ += __shfl_xor(p_, 8);
            p_ += __shfl_xor(p_, 4);
            p_ += __shfl_xor(p_, 2);
            p_ += __shfl_xor(p_, 1);
            float score = p_ * 0.088388347648318447f;   // 1/sqrt(128)
            float mn = fmaxf(m, score);
            float scale = __expf(m - mn);
            float pe = __expf(score - mn);
            den = den * scale + pe;
            f32x2 v01 = __builtin_amdgcn_cvt_pk_f32_fp8(kv.z, false);
            f32x2 v23 = __builtin_amdgcn_cvt_pk_f32_fp8(kv.z, true);
            f32x2 v45 = __builtin_amdgcn_cvt_pk_f32_fp8(kv.w, false);
            f32x2 v67 = __builtin_amdgcn_cvt_pk_f32_fp8(kv.w, true);
            acc[0] = fmaf(acc[0], scale, pe * v01.x);
            acc[1] = fmaf(acc[1], scale, pe * v01.y);
            acc[2] = fmaf(acc[2], scale, pe * v23.x);
            acc[3] = fmaf(acc[3], scale, pe * v23.y);
            acc[4] = fmaf(acc[4], scale, pe * v45.x);
            acc[5] = fmaf(acc[5], scale, pe * v45.y);
            acc[6] = fmaf(acc[6], scale, pe * v67.x);
            acc[7] = fmaf(acc[7], scale, pe * v67.y);
            m = mn;
            if (!haven) break;
            en = en2; sn = sn2; kv = kvn;
        }
    }

    float mo = __shfl_xor(m, 16);
    float m2 = fmaxf(m, mo);
    mo = __shfl_xor(m2, 32);
    float mf = fmaxf(m2, mo);
    float sc = __expf(m - mf);
    den *= sc;
    den += __shfl_xor(den, 16);
    den += __shfl_xor(den, 32);
    #pragma unroll
    for (int c = 0; c < 8; ++c) {
        float a = acc[c] * sc;
        a += __shfl_xor(a, 16);
        a += __shfl_xor(a, 32);
        acc[c] = a;
    }
    float inv = den > 0.f ? 1.0f / den : 0.f;
    if (g == 0) {
        u16x8 s8 = *(const u16x8*)(sb + (size_t)node * DD + j * 8);
        u16x8 o8;
        #pragma unroll
        for (int c = 0; c < 8; ++c)
            o8[c] = f2bf(fmaxf(fmaf(acc[c], inv, bf2f(s8[c])), 0.f));
        *(u16x8*)(hout + (size_t)node * DD + j * 8) = o8;
    }
}

// ---------------- global mean pool (h bf16): segmented running sum ----------

__global__ __launch_bounds__(128) void pool_kernel(const unsigned short* __restrict__ h,
                                                   const int* __restrict__ batch,
                                                   float* __restrict__ gsum,
                                                   float* __restrict__ gcnt, int n) {
    __shared__ int bsh[PCHUNK];
    int t = threadIdx.x;
    int node0 = blockIdx.x * PCHUNK;
    int nnodes = min(PCHUNK, n - node0);
    if (t < nnodes) bsh[t] = batch[node0 + t];
    __syncthreads();

    int cur = bsh[0];
    float acc = 0.f;
    int cnt = 0;
    for (int j = 0; j < nnodes; ++j) {
        int g = bsh[j];
        float val = bf2f(h[(size_t)(node0 + j) * DD + t]);
        if (g != cur) {
            atomicAdd(&gsum[cur * DD + t], acc);
            if (t == 0) atomicAdd(&gcnt[cur], (float)cnt);
            acc = 0.f; cnt = 0; cur = g;
        }
        acc += val; ++cnt;
    }
    if (cnt > 0) {
        atomicAdd(&gsum[cur * DD + t], acc);
        if (t == 0) atomicAdd(&gcnt[cur], (float)cnt);
    }
}

// ---------------- FC + log_softmax ----------------

__global__ __launch_bounds__(64) void head_kernel(
    const float* __restrict__ gsum, const float* __restrict__ gcnt,
    const float* __restrict__ wfc, const float* __restrict__ bfc,
    float* __restrict__ out) {
    int g = blockIdx.x;
    int lane = threadIdx.x;
    float cnt = fmaxf(gcnt[g], 1.0f);
    float inv = 1.0f / cnt;
    float p0 = gsum[g * DD + lane] * inv;
    float p1 = gsum[g * DD + lane + 64] * inv;
    __shared__ float logits[NCLS];
    for (int c = 0; c < NCLS; ++c) {
        float partial = p0 * wfc[lane * NCLS + c] + p1 * wfc[(lane + 64) * NCLS + c];
        partial += __shfl_xor(partial, 32);
        partial += __shfl_xor(partial, 16);
        partial += __shfl_xor(partial, 8);
        partial += __shfl_xor(partial, 4);
        partial += __shfl_xor(partial, 2);
        partial += __shfl_xor(partial, 1);
        if (lane == 0) logits[c] = partial + bfc[c];
    }
    __syncthreads();
    if (lane == 0) {
        float mx = logits[0];
        for (int c = 1; c < NCLS; ++c) mx = fmaxf(mx, logits[c]);
        float sum = 0.f;
        for (int c = 0; c < NCLS; ++c) sum += expf(logits[c] - mx);
        float lse = mx + logf(sum);
        for (int c = 0; c < NCLS; ++c) out[g * NCLS + c] = logits[c] - lse;
    }
}

// ---------------- launch ----------------

extern "C" void kernel_launch(void* const* d_in, const int* in_sizes, int n_in,
                              void* d_out, int out_size, void* d_ws, size_t ws_size,
                              hipStream_t stream) {
    const float* x     = (const float*)d_in[0];
    const int*   ei    = (const int*)d_in[1];
    const int*   batch = (const int*)d_in[2];
    const float* Wq = (const float*)d_in[3];
    const float* bq = (const float*)d_in[4];
    const float* Wk = (const float*)d_in[5];
    const float* bk = (const float*)d_in[6];
    const float* Wv = (const float*)d_in[7];
    const float* bv = (const float*)d_in[8];
    const float* Ws = (const float*)d_in[9];
    const float* bs = (const float*)d_in[10];
    const float* Wfc = (const float*)d_in[11];
    const float* bfc = (const float*)d_in[12];
    float* out = (float*)d_out;

    const size_t ND = (size_t)NN * DD;
    unsigned short* hbuf = (unsigned short*)d_ws;   // bf16
    unsigned short* qb  = hbuf + ND;
    unsigned short* sb  = qb + ND;
    unsigned short* kvb = sb + ND;                  // [NN][256] bf16: k | v
    unsigned short* wt  = kvb + 2 * ND;             // [2][4][128][128] bf16
    unsigned char*  kv8 = (unsigned char*)(wt + 2 * 4 * 16384);  // [NN][256] fp8 packed
    int* bucketcnt = (int*)(kv8 + (size_t)NN * 256);
    int* indptr    = bucketcnt + 256;               // [NN+1]
    int* esrc      = indptr + NN + 1;               // [EE]
    int2* bedge    = (int2*)(esrc + EE);            // [NBUK*BSTRIDE]
    float* gsum = (float*)(bedge + NBUK * BSTRIDE);
    float* gcnt = gsum + GG * DD;

    const int* src = ei;
    const int* dst = ei + EE;

    prep_kernel<<<256, 256, 0, stream>>>(Wq, Wk, Wv, Ws, wt, bucketcnt, gsum);
    bucket_kernel<<<256, 1024, 0, stream>>>(src, dst, bucketcnt, bedge);
    bsort_kernel<<<NBUK, 1024, 0, stream>>>(bucketcnt, bedge, indptr, esrc);

    for (int l = 0; l < 2; ++l) {
        size_t bo = (size_t)l * DD;
        const unsigned short* wtl = wt + (size_t)l * 4 * 16384;
        if (l == 0)
            gemm_mfma<false><<<512, 256, 0, stream>>>(
                (const void*)x, wtl, bq + bo, bk + bo, bv + bo, bs + bo,
                qb, kvb, sb);
        else
            gemm_mfma<true><<<512, 256, 0, stream>>>(
                (const void*)hbuf, wtl, bq + bo, bk + bo, bv + bo, bs + bo,
                qb, kvb, sb);
        kv8_kernel<<<(NN * 16) / 256, 256, 0, stream>>>(kvb, kv8);
        attn_kernel<<<(NN + 3) / 4, 256, 0, stream>>>(
            qb, kv8, sb, indptr, esrc, hbuf, NN);
    }

    pool_kernel<<<(NN + PCHUNK - 1) / PCHUNK, 128, 0, stream>>>(hbuf, batch, gsum, gcnt, NN);
    head_kernel<<<GG, 64, 0, stream>>>(gsum, gcnt, Wfc, bfc, out);
}